// Round 5
// baseline (507.412 us; speedup 1.0000x reference)
//
#include <hip/hip_runtime.h>
#include <hip/hip_bf16.h>

typedef __attribute__((ext_vector_type(8))) short bf16x8;
typedef __attribute__((ext_vector_type(4))) float f32x4;
typedef unsigned short u16;
typedef unsigned int u32;

__device__ __forceinline__ u16 f2bf(float f){
    u32 u; __builtin_memcpy(&u,&f,4);
    u = (u + 0x7FFFu + ((u>>16)&1u)) >> 16;
    return (u16)u;
}
__device__ __forceinline__ float bf2f(u16 h){
    u32 u = ((u32)h)<<16; float f; __builtin_memcpy(&f,&u,4); return f;
}
__device__ __forceinline__ u32 pkbf(float a, float b){
    __hip_bfloat162 h = __float22bfloat162_rn(float2{a,b});
    u32 r; __builtin_memcpy(&r,&h,4); return r;
}
// tanh via v_exp_f32 (2^x) + v_rcp_f32 — no slow div sequence
__device__ __forceinline__ float fast_tanh(float x){
    float e = __builtin_amdgcn_exp2f(x * 2.8853900817779268f);
    return 1.f - 2.f*__builtin_amdgcn_rcpf(e + 1.f);
}
__device__ __forceinline__ float wval(const float* W, int d, int e){
    return (d<300 && e<300) ? W[d*300+e] : 0.f;
}

// ---------------- K0: weight prep (swizzle to MFMA fragment order) ----------
// frag[tile][ks][lane][j] = W[d=tile*16+(lane&15)][e=ks*32+(lane>>4)*8+j]
__global__ void k_prep(const float* __restrict__ Wy, const float* __restrict__ Wh,
                       const float* __restrict__ Wp, const float* __restrict__ Wx,
                       const float* __restrict__ w,
                       u16* __restrict__ wy_swz, u16* __restrict__ wh_swz,
                       u16* __restrict__ wpx_swz, float* __restrict__ w_pad)
{
    int gid = blockIdx.x*256 + threadIdx.x;
    if (gid < 320) w_pad[gid] = (gid < 300) ? w[gid] : 0.f;
    u16* dst; const float* A; const float* Bm = nullptr; int t, nks;
    if (gid < 12800)      { dst = wy_swz;  t = gid;        nks = 10; A = Wy; }
    else if (gid < 25600) { dst = wh_swz;  t = gid-12800;  nks = 10; A = Wh; }
    else                  { dst = wpx_swz; t = gid-25600;  nks = 20; A = Wp; Bm = Wx; }
    int ks   = (t/64) % nks;
    int tile = t/(nks*64);
    int lane = t & 63;
    int d  = tile*16 + (lane & 15);
    int kb = ks*32 + (lane>>4)*8;
    u32 pk[4];
    #pragma unroll
    for (int jj=0; jj<4; jj++){
        int k0 = kb + 2*jj, k1 = k0 + 1;
        float v0, v1;
        if (Bm){ v0 = (k0 < 320) ? wval(A,d,k0) : wval(Bm,d,k0-320);
                 v1 = (k1 < 320) ? wval(A,d,k1) : wval(Bm,d,k1-320); }
        else   { v0 = wval(A,d,k0); v1 = wval(A,d,k1); }
        pk[jj] = (u32)f2bf(v0) | ((u32)f2bf(v1) << 16);
    }
    uint4 u; u.x = pk[0]; u.y = pk[1]; u.z = pk[2]; u.w = pk[3];
    ((uint4*)dst)[t] = u;
}

// ---------------- K1: Whh = h_n @ Wh^T  ->  bf16 [B][320] -------------------
__global__ __launch_bounds__(256,3) void k_whh(const float* __restrict__ hn,
        const u16* __restrict__ wh_swz, u16* __restrict__ whh)
{
    __shared__ __align__(16) u16 A[64*328];
    int tid = threadIdx.x;
    int rb = blockIdx.x >> 1, half = blockIdx.x & 1;
    int m0 = rb*64;
    for (int i = tid; i < 9600; i += 256){
        int r = i/150, c = (i%150)*2;
        float2 v = *(const float2*)(hn + (size_t)(m0+r)*300 + c);
        *(u32*)&A[r*328 + c] = pkbf(v.x, v.y);
    }
    for (int i = tid; i < 64*14; i += 256){ int r = i/14, c = 300 + (i%14)*2; *(u32*)&A[r*328+c] = 0; }
    __syncthreads();
    int w = tid>>6, lane = tid&63, lo = lane&15, hi = lane>>4;
    f32x4 acc[10];
    #pragma unroll
    for (int t=0; t<10; t++) acc[t] = (f32x4){0.f,0.f,0.f,0.f};
    const bf16x8* wsz = (const bf16x8*)wh_swz;
    for (int ks=0; ks<10; ks++){
        bf16x8 aF = *(const bf16x8*)&A[(w*16+lo)*328 + ks*32 + hi*8];
        #pragma unroll
        for (int t=0; t<10; t++){
            int nt = half*10 + t;
            bf16x8 bF = wsz[(nt*10+ks)*64 + lane];
            acc[t] = __builtin_amdgcn_mfma_f32_16x16x32_bf16(aF, bF, acc[t], 0,0,0);
        }
    }
    #pragma unroll
    for (int t=0; t<10; t++)
      #pragma unroll
      for (int rg=0; rg<4; rg++){
        int m = m0 + w*16 + hi*4 + rg;
        whh[(size_t)m*320 + (half*10+t)*16 + lo] = f2bf(acc[t][rg]);
      }
}

// ---------------- K2: fused attention main (1 batch / block) ----------------
// Ylds: transposed bf16 [row=l (50)][e (328 u16 stride)], NO swizzle.
//   stride 328 u16 = 164 words == 4 (mod 32) -> b128 reads conflict-free.
__global__ __launch_bounds__(256,4) void k_attn(const float* __restrict__ Y,
        const u16* __restrict__ whh, const u16* __restrict__ wy_swz,
        const float* __restrict__ w_pad, u16* __restrict__ r_out)
{
    __shared__ __align__(16) u16 Ylds[50*328];     // 32800 B
    __shared__ float whh_s[320];
    __shared__ float w_s[320];
    __shared__ float s_red[4][64];
    __shared__ float alpha_s[64];
    char* Yb8 = (char*)Ylds;
    int tid = threadIdx.x;
    int b = blockIdx.x;
    int w = tid>>6, lane = tid&63, lo = lane&15, hi = lane>>4;
    const float* Yb = Y + (size_t)b*15000;
    const float C2L = 2.8853900817779268f;         // 2*log2(e)

    // ---- staging: e-quad tasks. task t: e4=t/12 (rows e=4e4..4e4+3), l4=(t%12)*4
#define STAGE_TASK(T) do{                                                     \
        int e4 = (T)/12, l4 = ((T)%12)*4;                                     \
        const float* p0 = Yb + e4*200 + l4;                                   \
        float4 r0 = *(const float4*)p0;                                       \
        float2 r1a = *(const float2*)(p0+50), r1b = *(const float2*)(p0+52);  \
        float4 r2 = *(const float4*)(p0+100);                                 \
        float2 r3a = *(const float2*)(p0+150), r3b = *(const float2*)(p0+152);\
        float e0v[4]={r0.x,r0.y,r0.z,r0.w};                                   \
        float e1v[4]={r1a.x,r1a.y,r1b.x,r1b.y};                               \
        float e2v[4]={r2.x,r2.y,r2.z,r2.w};                                   \
        float e3v[4]={r3a.x,r3a.y,r3b.x,r3b.y};                               \
        _Pragma("unroll")                                                     \
        for (int j=0;j<4;j++){                                                \
            int row = l4+j;                                                   \
            uint2 uu; uu.x = pkbf(e0v[j], e1v[j]); uu.y = pkbf(e2v[j], e3v[j]);\
            *(uint2*)(Yb8 + row*656 + e4*8) = uu;                             \
        } }while(0)

    {
        #pragma unroll
        for (int it=0; it<3; it++){ int t = tid + it*256; STAGE_TASK(t); }
        if (tid < 132){ int t = tid + 768; STAGE_TASK(t); }
    }
#undef STAGE_TASK
    if (tid < 75){                                 // tail rows l=48,49
        int e4 = tid;
        const float* p0 = Yb + e4*200;
        float2 a0 = *(const float2*)(p0+48);
        float2 a1 = *(const float2*)(p0+98);
        float2 a2 = *(const float2*)(p0+148);
        float2 a3 = *(const float2*)(p0+198);
        uint2 u48; u48.x = pkbf(a0.x, a1.x); u48.y = pkbf(a2.x, a3.x);
        uint2 u49; u49.x = pkbf(a0.y, a1.y); u49.y = pkbf(a2.y, a3.y);
        *(uint2*)(Yb8 + 48*656 + e4*8) = u48;
        *(uint2*)(Yb8 + 49*656 + e4*8) = u49;
    }
    if (tid < 250){                                // zero e in [300,320), rows 0..49
        int row = tid/5, q = tid%5;
        uint2 z; z.x = 0; z.y = 0;
        *(uint2*)(Yb8 + row*656 + 600 + q*8) = z;
    }
    for (int i = tid; i < 160; i += 256){
        u32 z = *(const u32*)&whh[(size_t)b*320 + 2*i];
        whh_s[2*i]   = bf2f((u16)(z & 0xffff));
        whh_s[2*i+1] = bf2f((u16)(z >> 16));
    }
    for (int i = tid; i < 320; i += 256) w_s[i] = w_pad[i];
    __syncthreads();

    // ---- G = Wy * Yb, two q-passes, 2-deep pipelined fragment loads ----
    const bf16x8* wyf = (const bf16x8*)wy_swz;
    float sp[4] = {0.f,0.f,0.f,0.f};
    float swd = 0.f;
    int rb_[4];
    #pragma unroll
    for (int c=0;c<4;c++){ int row=c*16+lo; if (row>=50) row-=48; rb_[c]=row*656; }
    int hi16 = hi*16;

#define GEMM_PASS(Q0, NQ)                                                      \
    {                                                                          \
        f32x4 acc[NQ][4];                                                      \
        _Pragma("unroll") for (int q=0;q<NQ;q++)                               \
            _Pragma("unroll") for (int c=0;c<4;c++)                            \
                acc[q][c] = (f32x4){0.f,0.f,0.f,0.f};                          \
        bf16x8 A0[NQ], A1[NQ], B0[4], B1[4];                                   \
        _Pragma("unroll") for (int q=0;q<NQ;q++)                               \
            A0[q] = wyf[((w+4*((Q0)+q))*10)*64 + lane];                        \
        _Pragma("unroll") for (int c=0;c<4;c++)                                \
            B0[c] = *(const bf16x8*)(Yb8 + rb_[c] + hi16);                     \
        _Pragma("unroll 1")                                                    \
        for (int kk=0; kk<5; kk++){                                            \
            int k1 = 2*kk+1, k2 = 2*kk+2;                                      \
            int k2c = (k2 < 10) ? k2 : 0;                                      \
            _Pragma("unroll") for (int q=0;q<NQ;q++)                           \
                A1[q] = wyf[((w+4*((Q0)+q))*10 + k1)*64 + lane];               \
            _Pragma("unroll") for (int c=0;c<4;c++)                            \
                B1[c] = *(const bf16x8*)(Yb8 + rb_[c] + k1*64 + hi16);         \
            _Pragma("unroll") for (int q=0;q<NQ;q++)                           \
                _Pragma("unroll") for (int c=0;c<4;c++)                        \
                    acc[q][c] = __builtin_amdgcn_mfma_f32_16x16x32_bf16(       \
                        A0[q], B0[c], acc[q][c], 0,0,0);                       \
            _Pragma("unroll") for (int q=0;q<NQ;q++)                           \
                A0[q] = wyf[((w+4*((Q0)+q))*10 + k2)*64 + lane];               \
            _Pragma("unroll") for (int c=0;c<4;c++)                            \
                B0[c] = *(const bf16x8*)(Yb8 + rb_[c] + k2c*64 + hi16);        \
            _Pragma("unroll") for (int q=0;q<NQ;q++)                           \
                _Pragma("unroll") for (int c=0;c<4;c++)                        \
                    acc[q][c] = __builtin_amdgcn_mfma_f32_16x16x32_bf16(       \
                        A1[q], B1[c], acc[q][c], 0,0,0);                       \
        }                                                                      \
        _Pragma("unroll") for (int q=0;q<NQ;q++)                               \
            _Pragma("unroll") for (int rg=0;rg<4;rg++){                        \
                int d = (w + 4*((Q0)+q))*16 + hi*4 + rg;                       \
                float wh = whh_s[d], wd_ = w_s[d];                             \
                float whc = wh*C2L, wd2n = -2.f*wd_;                           \
                swd += wd_;                                                    \
                _Pragma("unroll") for (int c=0;c<4;c++){                       \
                    float targ = __builtin_fmaf(acc[q][c][rg], C2L, whc);      \
                    float e2x  = __builtin_amdgcn_exp2f(targ);                 \
                    float rc   = __builtin_amdgcn_rcpf(e2x + 1.f);             \
                    sp[c] = __builtin_fmaf(wd2n, rc, sp[c]);                   \
                }                                                              \
            }                                                                  \
    }

    GEMM_PASS(0, 3)
    GEMM_PASS(3, 2)
#undef GEMM_PASS

    #pragma unroll
    for (int c=0;c<4;c++){
        sp[c] += swd;                 // sum w*tanh = sum(w) - 2*sum(w*rcp)
        sp[c] += __shfl_xor(sp[c], 16);
        sp[c] += __shfl_xor(sp[c], 32);
    }
    if (lane < 16){
        #pragma unroll
        for (int c=0;c<4;c++) s_red[w][c*16 + lane] = sp[c];
    }
    __syncthreads();

    // ---- softmax over l (wave 0) ----
    if (w == 0){
        float sv = (lane < 50)
            ? (s_red[0][lane] + s_red[1][lane] + s_red[2][lane] + s_red[3][lane])
            : -1e30f;
        float mx = sv;
        #pragma unroll
        for (int off=32; off; off>>=1) mx = fmaxf(mx, __shfl_xor(mx, off));
        float pv = (lane < 50) ? __builtin_amdgcn_exp2f((sv - mx)*1.4426950408889634f) : 0.f;
        float sm = pv;
        #pragma unroll
        for (int off=32; off; off>>=1) sm += __shfl_xor(sm, off);
        alpha_s[lane] = pv * __builtin_amdgcn_rcpf(sm);
    }
    __syncthreads();

    // ---- r[d] = sum_l Y[d][l] * alpha[l] ----
    if (tid < 160){
        float r0 = 0.f, r1 = 0.f;
        if (tid < 150){
            #pragma unroll 10
            for (int l=0; l<50; l++){
                u32 z = *(const u32*)(Yb8 + l*656 + tid*4);
                float a_ = alpha_s[l];
                r0 += a_ * bf2f((u16)(z & 0xffff));
                r1 += a_ * bf2f((u16)(z >> 16));
            }
        }
        *(u32*)&r_out[(size_t)b*320 + 2*tid] = pkbf(r0, r1);
    }
}

// ---------------- K3: h = tanh([r|hn] @ [Wp|Wx]^T), 32 rows/block -----------
__global__ __launch_bounds__(256,3) void k_out(const u16* __restrict__ r_in,
        const float* __restrict__ hn, const u16* __restrict__ wpx_swz,
        float* __restrict__ out)
{
    __shared__ __align__(16) u16 A[32*648];
    int tid = threadIdx.x;
    int m0 = blockIdx.x*32;
    for (int i = tid; i < 32*40; i += 256){
        int r = i/40, c8 = (i%40)*8;
        uint4 v = *(const uint4*)&r_in[(size_t)(m0+r)*320 + c8];
        *(uint4*)&A[r*648 + c8] = v;
    }
    for (int i = tid; i < 32*150; i += 256){
        int r = i/150, c = (i%150)*2;
        float2 v = *(const float2*)(hn + (size_t)(m0+r)*300 + c);
        *(u32*)&A[r*648 + 320 + c] = pkbf(v.x, v.y);
    }
    for (int i = tid; i < 32*14; i += 256){ int r = i/14, c = 620 + (i%14)*2; *(u32*)&A[r*648+c] = 0; }
    __syncthreads();
    int w = tid>>6, lane = tid&63, lo = lane&15, hi = lane>>4;
    int wm = w & 1, wn = w >> 1;
    f32x4 acc[10];
    #pragma unroll
    for (int t=0; t<10; t++) acc[t] = (f32x4){0.f,0.f,0.f,0.f};
    const bf16x8* wsz = (const bf16x8*)wpx_swz;
    for (int ks=0; ks<20; ks++){
        bf16x8 aF = *(const bf16x8*)&A[(wm*16+lo)*648 + ks*32 + hi*8];
        #pragma unroll
        for (int t=0; t<10; t++){
            int nt = wn*10 + t;
            bf16x8 bF = wsz[(nt*20+ks)*64 + lane];
            acc[t] = __builtin_amdgcn_mfma_f32_16x16x32_bf16(aF, bF, acc[t], 0,0,0);
        }
    }
    #pragma unroll
    for (int t=0; t<10; t++){
        int n = (wn*10+t)*16 + lo;
        if (n < 300){
            #pragma unroll
            for (int rg=0; rg<4; rg++){
                int m = m0 + wm*16 + hi*4 + rg;
                out[(size_t)m*300 + n] = fast_tanh(acc[t][rg]);
            }
        }
    }
}

extern "C" void kernel_launch(void* const* d_in, const int* in_sizes, int n_in,
                              void* d_out, int out_size, void* d_ws, size_t ws_size,
                              hipStream_t stream)
{
    const float* Y  = (const float*)d_in[0];
    const float* hn = (const float*)d_in[1];
    const float* Wy = (const float*)d_in[2];
    const float* Wh = (const float*)d_in[3];
    const float* Wp = (const float*)d_in[4];
    const float* Wx = (const float*)d_in[5];
    const float* w  = (const float*)d_in[6];
    int B = in_sizes[1] / 300;                       // 16384

    char* ws = (char*)d_ws;
    u16*   wy_swz  = (u16*)(ws + 0);                 // 204800 B
    u16*   wh_swz  = (u16*)(ws + 204800);            // 204800 B
    u16*   wpx_swz = (u16*)(ws + 409600);            // 409600 B
    float* w_pad   = (float*)(ws + 819200);          // 1280 B
    u16*   whh     = (u16*)(ws + 820480);            // B*320*2
    u16*   r_ws    = (u16*)(ws + 820480 + (size_t)B*640);

    k_prep<<<200, 256, 0, stream>>>(Wy, Wh, Wp, Wx, w, wy_swz, wh_swz, wpx_swz, w_pad);
    k_whh <<<(B/64)*2, 256, 0, stream>>>(hn, wh_swz, whh);
    k_attn<<<B, 256, 0, stream>>>(Y, whh, wy_swz, w_pad, r_ws);
    k_out <<<B/32, 256, 0, stream>>>(r_ws, hn, wpx_swz, (float*)d_out);
}

// Round 10
// 485.588 us; speedup vs baseline: 1.0449x; 1.0449x over previous
//
#include <hip/hip_runtime.h>
#include <hip/hip_bf16.h>

typedef __attribute__((ext_vector_type(8))) short bf16x8;
typedef __attribute__((ext_vector_type(4))) float f32x4;
typedef unsigned short u16;
typedef unsigned int u32;

__device__ __forceinline__ u16 f2bf(float f){
    u32 u; __builtin_memcpy(&u,&f,4);
    u = (u + 0x7FFFu + ((u>>16)&1u)) >> 16;
    return (u16)u;
}
__device__ __forceinline__ float bf2f(u16 h){
    u32 u = ((u32)h)<<16; float f; __builtin_memcpy(&f,&u,4); return f;
}
__device__ __forceinline__ u32 pkbf(float a, float b){
    __hip_bfloat162 h = __float22bfloat162_rn(float2{a,b});
    u32 r; __builtin_memcpy(&r,&h,4); return r;
}
__device__ __forceinline__ float fast_tanh(float x){
    float e = __builtin_amdgcn_exp2f(x * 2.8853900817779268f);
    return 1.f - 2.f*__builtin_amdgcn_rcpf(e + 1.f);
}
__device__ __forceinline__ float wval(const float* W, int d, int e){
    return (d<300 && e<300) ? W[d*300+e] : 0.f;
}

// ---------------- K0: weight prep (swizzle to MFMA fragment order) ----------
__global__ void k_prep(const float* __restrict__ Wy, const float* __restrict__ Wh,
                       const float* __restrict__ Wp, const float* __restrict__ Wx,
                       const float* __restrict__ w,
                       u16* __restrict__ wy_swz, u16* __restrict__ wh_swz,
                       u16* __restrict__ wpx_swz, float* __restrict__ w_pad)
{
    int gid = blockIdx.x*256 + threadIdx.x;
    if (gid < 320) w_pad[gid] = (gid < 300) ? w[gid] : 0.f;
    u16* dst; const float* A; const float* Bm = nullptr; int t, nks;
    if (gid < 12800)      { dst = wy_swz;  t = gid;        nks = 10; A = Wy; }
    else if (gid < 25600) { dst = wh_swz;  t = gid-12800;  nks = 10; A = Wh; }
    else                  { dst = wpx_swz; t = gid-25600;  nks = 20; A = Wp; Bm = Wx; }
    int ks   = (t/64) % nks;
    int tile = t/(nks*64);
    int lane = t & 63;
    int d  = tile*16 + (lane & 15);
    int kb = ks*32 + (lane>>4)*8;
    u32 pk[4];
    #pragma unroll
    for (int jj=0; jj<4; jj++){
        int k0 = kb + 2*jj, k1 = k0 + 1;
        float v0, v1;
        if (Bm){ v0 = (k0 < 320) ? wval(A,d,k0) : wval(Bm,d,k0-320);
                 v1 = (k1 < 320) ? wval(A,d,k1) : wval(Bm,d,k1-320); }
        else   { v0 = wval(A,d,k0); v1 = wval(A,d,k1); }
        pk[jj] = (u32)f2bf(v0) | ((u32)f2bf(v1) << 16);
    }
    uint4 u; u.x = pk[0]; u.y = pk[1]; u.z = pk[2]; u.w = pk[3];
    ((uint4*)dst)[t] = u;
}

// ---------------- K1: Whh = h_n @ Wh^T  ->  bf16 [B][320] -------------------
__global__ __launch_bounds__(256,3) void k_whh(const float* __restrict__ hn,
        const u16* __restrict__ wh_swz, u16* __restrict__ whh)
{
    __shared__ __align__(16) u16 A[64*328];
    int tid = threadIdx.x;
    int rb = blockIdx.x >> 1, half = blockIdx.x & 1;
    int m0 = rb*64;
    for (int i = tid; i < 9600; i += 256){
        int r = i/150, c = (i%150)*2;
        float2 v = *(const float2*)(hn + (size_t)(m0+r)*300 + c);
        *(u32*)&A[r*328 + c] = pkbf(v.x, v.y);
    }
    for (int i = tid; i < 64*14; i += 256){ int r = i/14, c = 300 + (i%14)*2; *(u32*)&A[r*328+c] = 0; }
    __syncthreads();
    int w = tid>>6, lane = tid&63, lo = lane&15, hi = lane>>4;
    f32x4 acc[10];
    #pragma unroll
    for (int t=0; t<10; t++) acc[t] = (f32x4){0.f,0.f,0.f,0.f};
    const bf16x8* wsz = (const bf16x8*)wh_swz;
    for (int ks=0; ks<10; ks++){
        bf16x8 aF = *(const bf16x8*)&A[(w*16+lo)*328 + ks*32 + hi*8];
        #pragma unroll
        for (int t=0; t<10; t++){
            int nt = half*10 + t;
            bf16x8 bF = wsz[(nt*10+ks)*64 + lane];
            acc[t] = __builtin_amdgcn_mfma_f32_16x16x32_bf16(aF, bF, acc[t], 0,0,0);
        }
    }
    #pragma unroll
    for (int t=0; t<10; t++)
      #pragma unroll
      for (int rg=0; rg<4; rg++){
        int m = m0 + w*16 + hi*4 + rg;
        whh[(size_t)m*320 + (half*10+t)*16 + lo] = f2bf(acc[t][rg]);
      }
}

// ---------------- K2: fused attention, 1 batch / 1024-thread block ----------
// BISECT ROUND: 1024-thread GEMM core (16 waves, wd/wc decomp) but NO
// persistence/pipeline; softmax+r in the R4-proven alpha_s LDS form.
__global__ __launch_bounds__(1024) void k_attn(const float* __restrict__ Y,
        const u16* __restrict__ whh, const u16* __restrict__ wy_swz,
        const float* __restrict__ w_pad, u16* __restrict__ r_out)
{
    __shared__ __align__(16) u16 Ylds[50*328];   // 32800 B, transposed bf16
    __shared__ float whh_s[320];
    __shared__ float w_s[320];
    __shared__ float s_red[8][64];
    __shared__ float alpha_s[64];

    const int tid = threadIdx.x;
    const int wv = tid>>6, lane = tid&63, lo = lane&15, hi = lane>>4;
    const int wd = wv>>1, wc = wv&1;
    const int hi16 = hi*16;
    const int b = blockIdx.x;
    char* Yb8 = (char*)Ylds;
    const float C2L = 2.8853900817779268f;       // 2*log2(e)

    // B-fragment row bases for this wave's two col-tiles (rows>=50 clamped)
    int rb_[2];
    { int r0 = (2*wc)*16 + lo;   if (r0>=50) r0-=48; rb_[0]=r0*656;
      int r1 = (2*wc+1)*16 + lo; if (r1>=50) r1-=48; rb_[1]=r1*656; }

    // ---- prologue: constants + staging (load -> cvt -> transposed write) ----
    for (int i = tid; i < 320; i += 1024) w_s[i] = w_pad[i];
    for (int i = tid; i < 700; i += 1024){       // zero u16 cols 300..327
        int row = i/14, c2 = 150 + i%14;
        *(u32*)(Yb8 + row*656 + c2*4) = 0;
    }
    for (int i = tid; i < 160; i += 1024){
        u32 z = *(const u32*)&whh[(size_t)b*320 + 2*i];
        whh_s[2*i]   = bf2f((u16)(z & 0xffff));
        whh_s[2*i+1] = bf2f((u16)(z >> 16));
    }
    {
        const float* gb_ = Y + (size_t)b*15000;
        #pragma unroll
        for (int it=0; it<4; it++){
            int t = tid + it*1024;
            if (t < 3750){
                int e2 = t/25, l2 = t%25;        // d-pair e2, l-pair l2
                const float* p_ = gb_ + e2*100 + 2*l2;
                float2 sA = *(const float2*)p_;          // row d=2e2
                float2 sB = *(const float2*)(p_ + 50);   // row d=2e2+1
                *(u32*)(Yb8 + (2*l2)*656   + e2*4) = pkbf(sA.x, sB.x);
                *(u32*)(Yb8 + (2*l2+1)*656 + e2*4) = pkbf(sA.y, sB.y);
            }
        }
    }
    __syncthreads();

    // ---- GEMM + tanh/w epilogue (16 waves: wd 0..7 x wc 0..1) ----
    const bf16x8* wyf = (const bf16x8*)wy_swz;
    float sp[2] = {0.f,0.f};
    float swd = 0.f;
#define GEMM_BODY(NT)                                                          \
    {                                                                          \
        f32x4 acc[NT][2];                                                      \
        _Pragma("unroll") for (int q=0;q<NT;q++){                              \
            acc[q][0]=(f32x4){0.f,0.f,0.f,0.f};                                \
            acc[q][1]=(f32x4){0.f,0.f,0.f,0.f}; }                              \
        bf16x8 A0[NT], A1[NT], B0[2], B1[2];                                   \
        _Pragma("unroll") for (int q=0;q<NT;q++)                               \
            A0[q] = wyf[((wd+8*q)*10)*64 + lane];                              \
        B0[0] = *(const bf16x8*)(Yb8 + rb_[0] + hi16);                         \
        B0[1] = *(const bf16x8*)(Yb8 + rb_[1] + hi16);                         \
        _Pragma("unroll 1")                                                    \
        for (int kk=0; kk<5; kk++){                                            \
            int k1 = 2*kk+1, k2 = (2*kk+2<10)?(2*kk+2):0;                      \
            _Pragma("unroll") for (int q=0;q<NT;q++)                           \
                A1[q] = wyf[((wd+8*q)*10 + k1)*64 + lane];                     \
            B1[0] = *(const bf16x8*)(Yb8 + rb_[0] + k1*64 + hi16);             \
            B1[1] = *(const bf16x8*)(Yb8 + rb_[1] + k1*64 + hi16);             \
            _Pragma("unroll") for (int q=0;q<NT;q++){                          \
                acc[q][0] = __builtin_amdgcn_mfma_f32_16x16x32_bf16(A0[q],B0[0],acc[q][0],0,0,0); \
                acc[q][1] = __builtin_amdgcn_mfma_f32_16x16x32_bf16(A0[q],B0[1],acc[q][1],0,0,0); } \
            _Pragma("unroll") for (int q=0;q<NT;q++)                           \
                A0[q] = wyf[((wd+8*q)*10 + k2)*64 + lane];                     \
            B0[0] = *(const bf16x8*)(Yb8 + rb_[0] + k2*64 + hi16);             \
            B0[1] = *(const bf16x8*)(Yb8 + rb_[1] + k2*64 + hi16);             \
            _Pragma("unroll") for (int q=0;q<NT;q++){                          \
                acc[q][0] = __builtin_amdgcn_mfma_f32_16x16x32_bf16(A1[q],B1[0],acc[q][0],0,0,0); \
                acc[q][1] = __builtin_amdgcn_mfma_f32_16x16x32_bf16(A1[q],B1[1],acc[q][1],0,0,0); } \
        }                                                                      \
        _Pragma("unroll") for (int q=0;q<NT;q++)                               \
            _Pragma("unroll") for (int rg=0;rg<4;rg++){                        \
                int d = (wd+8*q)*16 + hi*4 + rg;                               \
                float wh = whh_s[d], wd_ = w_s[d];                             \
                float whc = wh*C2L, wd2n = -2.f*wd_;                           \
                swd += wd_;                                                    \
                _Pragma("unroll") for (int c=0;c<2;c++){                       \
                    float targ = __builtin_fmaf(acc[q][c][rg], C2L, whc);      \
                    float e2x  = __builtin_amdgcn_exp2f(targ);                 \
                    float rc   = __builtin_amdgcn_rcpf(e2x + 1.f);             \
                    sp[c] = __builtin_fmaf(wd2n, rc, sp[c]);                   \
                }                                                              \
            }                                                                  \
    }
    if (wd < 3) { GEMM_BODY(3) } else { GEMM_BODY(2) }
#undef GEMM_BODY
    #pragma unroll
    for (int c=0;c<2;c++){
        sp[c] += swd;                 // sum w*tanh = sum(w) - 2*sum(w*rcp)
        sp[c] += __shfl_xor(sp[c], 16);
        sp[c] += __shfl_xor(sp[c], 32);
    }
    if (lane < 16){
        s_red[wd][(2*wc+0)*16 + lane] = sp[0];
        s_red[wd][(2*wc+1)*16 + lane] = sp[1];
    }
    __syncthreads();

    // ---- softmax over l (wave 0 only, R4-proven LDS-broadcast form) ----
    if (wv == 0){
        float sv = -1e30f;
        if (lane < 50){
            sv = 0.f;
            #pragma unroll
            for (int k=0;k<8;k++) sv += s_red[k][lane];
        }
        float mx = sv;
        #pragma unroll
        for (int off=32; off; off>>=1) mx = fmaxf(mx, __shfl_xor(mx, off));
        float pv = (lane < 50) ? __builtin_amdgcn_exp2f((sv - mx)*1.4426950408889634f) : 0.f;
        float sm = pv;
        #pragma unroll
        for (int off=32; off; off>>=1) sm += __shfl_xor(sm, off);
        alpha_s[lane] = pv * __builtin_amdgcn_rcpf(sm);
    }
    __syncthreads();

    // ---- r[d] = sum_l Y[d][l] * alpha[l] (R4-proven form) ----
    if (tid < 160){
        float r0 = 0.f, r1 = 0.f;
        if (tid < 150){
            #pragma unroll 10
            for (int l=0; l<50; l++){
                u32 z = *(const u32*)(Yb8 + l*656 + tid*4);
                float a_ = alpha_s[l];
                r0 = __builtin_fmaf(a_, bf2f((u16)(z & 0xffff)), r0);
                r1 = __builtin_fmaf(a_, bf2f((u16)(z >> 16)),   r1);
            }
        }
        *(u32*)&r_out[(size_t)b*320 + 2*tid] = pkbf(r0, r1);
    }
}

// ---------------- K3: h = tanh([r|hn] @ [Wp|Wx]^T), 32 rows/block -----------
__global__ __launch_bounds__(256,3) void k_out(const u16* __restrict__ r_in,
        const float* __restrict__ hn, const u16* __restrict__ wpx_swz,
        float* __restrict__ out)
{
    __shared__ __align__(16) u16 A[32*648];
    int tid = threadIdx.x;
    int m0 = blockIdx.x*32;
    for (int i = tid; i < 32*40; i += 256){
        int r = i/40, c8 = (i%40)*8;
        uint4 v = *(const uint4*)&r_in[(size_t)(m0+r)*320 + c8];
        *(uint4*)&A[r*648 + c8] = v;
    }
    for (int i = tid; i < 32*150; i += 256){
        int r = i/150, c = (i%150)*2;
        float2 v = *(const float2*)(hn + (size_t)(m0+r)*300 + c);
        *(u32*)&A[r*648 + 320 + c] = pkbf(v.x, v.y);
    }
    for (int i = tid; i < 32*14; i += 256){ int r = i/14, c = 620 + (i%14)*2; *(u32*)&A[r*648+c] = 0; }
    __syncthreads();
    int w = tid>>6, lane = tid&63, lo = lane&15, hi = lane>>4;
    int wm = w & 1, wn = w >> 1;
    f32x4 acc[10];
    #pragma unroll
    for (int t=0; t<10; t++) acc[t] = (f32x4){0.f,0.f,0.f,0.f};
    const bf16x8* wsz = (const bf16x8*)wpx_swz;
    for (int ks=0; ks<20; ks++){
        bf16x8 aF = *(const bf16x8*)&A[(wm*16+lo)*648 + ks*32 + hi*8];
        #pragma unroll
        for (int t=0; t<10; t++){
            int nt = wn*10 + t;
            bf16x8 bF = wsz[(nt*20+ks)*64 + lane];
            acc[t] = __builtin_amdgcn_mfma_f32_16x16x32_bf16(aF, bF, acc[t], 0,0,0);
        }
    }
    #pragma unroll
    for (int t=0; t<10; t++){
        int n = (wn*10+t)*16 + lo;
        if (n < 300){
            #pragma unroll
            for (int rg=0; rg<4; rg++){
                int m = m0 + wm*16 + hi*4 + rg;
                out[(size_t)m*300 + n] = fast_tanh(acc[t][rg]);
            }
        }
    }
}

extern "C" void kernel_launch(void* const* d_in, const int* in_sizes, int n_in,
                              void* d_out, int out_size, void* d_ws, size_t ws_size,
                              hipStream_t stream)
{
    const float* Y  = (const float*)d_in[0];
    const float* hn = (const float*)d_in[1];
    const float* Wy = (const float*)d_in[2];
    const float* Wh = (const float*)d_in[3];
    const float* Wp = (const float*)d_in[4];
    const float* Wx = (const float*)d_in[5];
    const float* w  = (const float*)d_in[6];
    int B = in_sizes[1] / 300;                       // 16384

    char* ws = (char*)d_ws;
    u16*   wy_swz  = (u16*)(ws + 0);                 // 204800 B
    u16*   wh_swz  = (u16*)(ws + 204800);            // 204800 B
    u16*   wpx_swz = (u16*)(ws + 409600);            // 409600 B
    float* w_pad   = (float*)(ws + 819200);          // 1280 B
    u16*   whh     = (u16*)(ws + 820480);            // B*320*2
    u16*   r_ws    = (u16*)(ws + 820480 + (size_t)B*640);

    k_prep<<<200, 256, 0, stream>>>(Wy, Wh, Wp, Wx, w, wy_swz, wh_swz, wpx_swz, w_pad);
    k_whh <<<(B/64)*2, 256, 0, stream>>>(hn, wh_swz, whh);
    k_attn<<<B, 1024, 0, stream>>>(Y, whh, wy_swz, w_pad, r_ws);
    k_out <<<B/32, 256, 0, stream>>>(r_ws, hn, wpx_swz, (float*)d_out);
}